// Round 2
// baseline (28.912 us; speedup 1.0000x reference)
//
#include <hip/hip_runtime.h>

// MultiHeadAttention with TRIPLE softmax along keys.
// softmax(softmax(softmax(scores))) == uniform(1/S) to ~1e-7 elementwise
// (2nd softmax flattens to 1/N + p/N, 3rd to 1/N + p/N^2). Hence
//   out[b,s,:] = ((mean_s' v[b,s',:]) @ Wv.T + bv) @ Wo.T + bo
// independent of q, k, Wq, Wk, padding_mask, and of s.
// Round-1 measured absmax 2.4e-4 vs threshold 2.34e-3.
//
// Round-2 structure: 5 kernels -> 3 (launch/gap-bound regime):
//   K1: partial column sums of v (float4)
//   K2: finalize mean (LDS) + t = vmean@Wv.T + bv   [fused]
//   K3: r = t@Wo.T + bo (redundant per s-chunk) + broadcast write [fused]

#define BATCH 4
#define SEQ 1024
#define DIM 1024
#define RCH 32            // row-chunks of 32 rows
#define D4 (DIM / 4)      // 256 float4 per row

// ---- K1: part[b][rc][d] = sum of 32 rows of v. grid (4, 4, 32), 64 thr ----
__global__ void k1_colsum_partial(const float4* __restrict__ v4,
                                  float4* __restrict__ part4) {
    const int b  = blockIdx.x;
    const int dh = blockIdx.y;                 // column quarter 0..3
    const int rc = blockIdx.z;                 // 0..31
    const int c  = dh * 64 + threadIdx.x;      // float4 column 0..255
    const float4* p = v4 + (size_t)(b * SEQ + rc * 32) * D4 + c;
    float4 s = {0.f, 0.f, 0.f, 0.f};
#pragma unroll
    for (int i = 0; i < 32; ++i) {
        float4 a = p[(size_t)i * D4];
        s.x += a.x; s.y += a.y; s.z += a.z; s.w += a.w;
    }
    part4[(size_t)(b * RCH + rc) * D4 + c] = s;
}

// ---- K2: vmean (LDS) + 32 dots vs Wv -> t. grid (4, 32), 256 thr ----
__global__ void k2_mid(const float4* __restrict__ part4,
                       const float4* __restrict__ Wv4,
                       const float* __restrict__ bv,
                       float* __restrict__ t) {
    __shared__ float4 vm[D4];
    const int b   = blockIdx.x;
    const int nch = blockIdx.y;                // 32 n's per block
    const int tid = threadIdx.x;

    // finalize mean: thread tid owns float4 column tid
    float4 s = {0.f, 0.f, 0.f, 0.f};
    const float4* p = part4 + (size_t)b * RCH * D4 + tid;
#pragma unroll
    for (int rc = 0; rc < RCH; ++rc) {
        float4 a = p[rc * D4];
        s.x += a.x; s.y += a.y; s.z += a.z; s.w += a.w;
    }
    const float inv = 1.0f / SEQ;
    s.x *= inv; s.y *= inv; s.z *= inv; s.w *= inv;
    vm[tid] = s;
    __syncthreads();

    const int wave = tid >> 6, lane = tid & 63;
#pragma unroll
    for (int i = 0; i < 8; ++i) {
        const int n = nch * 32 + wave * 8 + i;
        const float4* w = Wv4 + (size_t)n * D4;
        float acc = 0.f;
#pragma unroll
        for (int j = 0; j < 4; ++j) {
            float4 a  = vm[j * 64 + lane];
            float4 ww = w[j * 64 + lane];
            acc += a.x * ww.x + a.y * ww.y + a.z * ww.z + a.w * ww.w;
        }
#pragma unroll
        for (int off = 32; off > 0; off >>= 1) acc += __shfl_down(acc, off);
        if (lane == 0) t[b * DIM + n] = acc + bv[n];
    }
}

// ---- K3: r = t@Wo.T + bo, broadcast to 256 s rows. grid (4, 32, 4), 256 thr ----
__global__ void k3_out(const float4* __restrict__ t4,
                       const float4* __restrict__ Wo4,
                       const float* __restrict__ bo,
                       float4* __restrict__ out4) {
    __shared__ float4 tl[D4];
    __shared__ float4 r4[8];                   // 32 floats of r for this n-chunk
    const int b   = blockIdx.x;
    const int nch = blockIdx.y;                // 32 n's per block
    const int sch = blockIdx.z;                // 256 s rows per block
    const int tid = threadIdx.x;

    tl[tid] = t4[b * D4 + tid];
    __syncthreads();

    const int wave = tid >> 6, lane = tid & 63;
#pragma unroll
    for (int i = 0; i < 8; ++i) {
        const int nl = wave * 8 + i;           // 0..31
        const int n  = nch * 32 + nl;
        const float4* w = Wo4 + (size_t)n * D4;
        float acc = 0.f;
#pragma unroll
        for (int j = 0; j < 4; ++j) {
            float4 a  = tl[j * 64 + lane];
            float4 ww = w[j * 64 + lane];
            acc += a.x * ww.x + a.y * ww.y + a.z * ww.z + a.w * ww.w;
        }
#pragma unroll
        for (int off = 32; off > 0; off >>= 1) acc += __shfl_down(acc, off);
        if (lane == 0) ((float*)r4)[nl] = acc + bo[n];
    }
    __syncthreads();

    // broadcast: 256 s rows x 32 n (8 float4). thread -> (s0 = tid>>3, j4 = tid&7)
    const int j4 = tid & 7;
    const int s0 = tid >> 3;                   // 0..31
    const float4 val = r4[j4];
    const size_t nbase = (size_t)nch * 8 + j4;
#pragma unroll
    for (int it = 0; it < 8; ++it) {
        const int s = sch * 256 + it * 32 + s0;
        out4[(size_t)(b * SEQ + s) * D4 + nbase] = val;
    }
}

extern "C" void kernel_launch(void* const* d_in, const int* in_sizes, int n_in,
                              void* d_out, int out_size, void* d_ws, size_t ws_size,
                              hipStream_t stream) {
    const float* v  = (const float*)d_in[2];
    const float* Wv = (const float*)d_in[8];
    const float* bv = (const float*)d_in[9];
    const float* Wo = (const float*)d_in[10];
    const float* bo = (const float*)d_in[11];
    float* out = (float*)d_out;

    // Workspace: part (B*RCH*DIM floats = 512 KB) + t (B*DIM floats = 16 KB)
    float* part = (float*)d_ws;
    float* t    = part + (size_t)BATCH * RCH * DIM;

    k1_colsum_partial<<<dim3(BATCH, 4, RCH), 64, 0, stream>>>(
        (const float4*)v, (float4*)part);
    k2_mid<<<dim3(BATCH, 32), 256, 0, stream>>>(
        (const float4*)part, (const float4*)Wv, bv, t);
    k3_out<<<dim3(BATCH, 32, 4), 256, 0, stream>>>(
        (const float4*)t, (const float4*)Wo, bo, (float4*)out);
}